// Round 7
// baseline (177.051 us; speedup 1.0000x reference)
//
#include <hip/hip_runtime.h>

#define NBATCH 128
#define NANCH  8732
#define NCLS   21
#define SUBSX  8                        // blocks per batch
#define STEP   2048                     // anchors per stage chip-slice (8 blocks * 256)
// per block-stage: 256 anchors = 1344 cls float4 + 64 label float4 = 1408 f4
#define F4CLS  1344
#define F4ALL  1408
#define CLS_F4_MAX ((size_t)NBATCH * NANCH * NCLS / 4 - 1)
#define LAB_F4_MAX ((size_t)NBATCH * NANCH / 4 - 1)

// ws: float4 partial[NBATCH * SUBSX] -> 128*8*16 = 16384 bytes
// partial = { loc_sum, con_sum_all, con_sum_pos, pos_count }

// ---------------------------------------------------------------- helpers
__device__ __forceinline__ float waveReduceF(float v) {
    #pragma unroll
    for (int o = 32; o > 0; o >>= 1) v += __shfl_down(v, o, 64);
    return v;
}
__device__ __forceinline__ unsigned waveReduceU(unsigned v) {
    #pragma unroll
    for (int o = 32; o > 0; o >>= 1) v += __shfl_down(v, o, 64);
    return v;
}

__device__ __forceinline__ float con_from_row(const float* __restrict__ row, int lbl) {
    float m = row[0];
    #pragma unroll
    for (int c = 1; c < NCLS; ++c) m = fmaxf(m, row[c]);
    float s = 0.f;
    #pragma unroll
    for (int c = 0; c < NCLS; ++c) s += __expf(row[c] - m);
    return m + __logf(s) - row[lbl];
}

// async global -> LDS, 16 B/lane: HW writes lds_base + lane*16 (wave-uniform base)
__device__ __forceinline__ void gload_lds16(const float4* g, float4* l) {
    __builtin_amdgcn_global_load_lds(
        (const __attribute__((address_space(1))) void*)g,
        (__attribute__((address_space(3))) void*)l,
        16, 0, 0);
}

// counted waits; per-wave uniform (vmcnt is per-wave). sched_barrier stops
// later LDS reads being scheduled above the wait (m214 r263 pattern).
#define WAIT_PAIR(lo, hi)                                            \
    do {                                                             \
        if (wid < 2) asm volatile("s_waitcnt vmcnt(" #lo ")" ::: "memory"); \
        else         asm volatile("s_waitcnt vmcnt(" #hi ")" ::: "memory"); \
        __builtin_amdgcn_sched_barrier(0);                           \
    } while (0)

// ---------------------------------------------------------------- kernel 1
// T3+T4 never-drain DMA pipeline. 1024 blocks (8 x 128) * 256 thr, 5 stages
// of 256 anchors each (stride 2048). Each stage's cls rows + labels are DMA'd
// to one of 3 LDS buffers via global_load_lds; raw s_barrier (NO implicit
// vmcnt(0) drain, unlike __syncthreads) + per-wave counted s_waitcnt keep
// 2-3 stages (10-18 gload instr/wave, ~1 KB each) in flight at all times.
// Wave f4 split {0:5,320:5,640:6,1024:6} -> uniform vmcnt counts per wave.
// Phase 1 has zero VGPR-return global loads -> no compiler vmem waits.
__global__ __launch_bounds__(256, 2) void anchor_kernel(
    const float*  __restrict__ loc_out,   // [B,A,4]
    const float*  __restrict__ cls_out,   // [B,A,C]
    const float*  __restrict__ loc_lab,   // [B,A,4]
    const int*    __restrict__ labels,    // [B,A]
    float4* __restrict__ partial)         // [NBATCH*SUBSX]
{
    __shared__ float4 buf[3][F4ALL];      // 3 * 22528 B = 67584 B

    const int b   = blockIdx.y;
    const int s   = blockIdx.x;
    const int tid = threadIdx.x;
    const int wid = tid >> 6, lane = tid & 63;

    const size_t ba_blk = (size_t)b * NANCH + s * 256;   // %4 == 0
    const float4* cls4 = (const float4*)cls_out;
    const float4* lab4 = (const float4*)labels;

    const int wstart = (wid == 0) ? 0 : (wid == 1) ? 320 : (wid == 2) ? 640 : 1024;
    const int wcnt   = (wid < 2) ? 5 : 6;

    // ---- stage r into bufp: issue wcnt gload_lds (uniform per wave) ----
    auto stage = [&](float4* bufp, int r) {
        const size_t ba0     = ba_blk + (size_t)r * STEP;
        const size_t cls_f4b = ba0 * NCLS / 4;
        const size_t lab_f4b = ba0 / 4;
        for (int i = 0; i < wcnt; ++i) {
            const int uidx = wstart + i * 64;      // wave-uniform
            const int idx  = uidx + lane;          // per-lane
            const float4* src;
            if (uidx < F4CLS) {
                size_t g = cls_f4b + idx;
                if (g > CLS_F4_MAX) g = CLS_F4_MAX;
                src = cls4 + g;
            } else {
                size_t g = lab_f4b + (idx - F4CLS);
                if (g > LAB_F4_MAX) g = LAB_F4_MAX;
                src = lab4 + g;
            }
            gload_lds16(src, bufp + uidx);
        }
    };

    float all_s = 0.f, pos_s = 0.f, loc_s = 0.f;
    unsigned pc = 0;

    // ---- CE from LDS buffer; returns label (0 if invalid) ----
    auto compute_ce = [&](const float4* bufp, bool valid) -> int {
        if (!valid) return 0;
        const float* buff = (const float*)bufp;
        const int lbl = ((const int*)buff)[F4CLS * 4 + tid];
        const float* row = buff + tid * NCLS;
        float m = row[0];
        #pragma unroll
        for (int c = 1; c < NCLS; ++c) m = fmaxf(m, row[c]);
        float sum = 0.f;
        #pragma unroll
        for (int c = 0; c < NCLS; ++c) sum += __expf(row[c] - m);
        const float tgt = row[lbl];
        const float con = m + __logf(sum) - tgt;
        all_s += con;
        if (lbl > 0) { pos_s += con; pc++; }
        return lbl;
    };

    const bool v4 = (s * 256 + tid + 4 * STEP) < NANCH;   // stage-4 validity
    int lblA[5];

    // ---- prologue: 3 stages in flight ----
    stage(buf[0], 0);
    stage(buf[1], 1);
    stage(buf[2], 2);

    // r = 0
    WAIT_PAIR(10, 12);
    __builtin_amdgcn_s_barrier();
    lblA[0] = compute_ce(buf[0], true);
    __builtin_amdgcn_s_barrier();
    stage(buf[0], 3);
    // r = 1
    WAIT_PAIR(10, 12);
    __builtin_amdgcn_s_barrier();
    lblA[1] = compute_ce(buf[1], true);
    __builtin_amdgcn_s_barrier();
    stage(buf[1], 4);
    // r = 2
    WAIT_PAIR(10, 12);
    __builtin_amdgcn_s_barrier();
    lblA[2] = compute_ce(buf[2], true);
    // r = 3
    WAIT_PAIR(5, 6);
    __builtin_amdgcn_s_barrier();
    lblA[3] = compute_ce(buf[0], true);
    // r = 4
    WAIT_PAIR(0, 0);
    __builtin_amdgcn_s_barrier();
    lblA[4] = compute_ce(buf[1], v4);

    // ---- phase 2: SmoothL1 over positives (loc streams, ~27% of bytes) ----
    #pragma unroll
    for (int r = 0; r < 5; ++r) {
        if (lblA[r] > 0) {
            const size_t ba = ba_blk + (size_t)r * STEP + tid;
            const float4 lo4 = ((const float4*)loc_out)[ba];
            const float4 ll4 = ((const float4*)loc_lab)[ba];
            const float d0 = lo4.x - ll4.x, d1 = lo4.y - ll4.y,
                        d2 = lo4.z - ll4.z, d3 = lo4.w - ll4.w;
            const float a0 = fabsf(d0), a1 = fabsf(d1),
                        a2 = fabsf(d2), a3 = fabsf(d3);
            loc_s += ((a0 < 1.f) ? 0.5f * d0 * d0 : (a0 - 0.5f))
                   + ((a1 < 1.f) ? 0.5f * d1 * d1 : (a1 - 0.5f))
                   + ((a2 < 1.f) ? 0.5f * d2 * d2 : (a2 - 0.5f))
                   + ((a3 < 1.f) ? 0.5f * d3 * d3 : (a3 - 0.5f));
        }
    }

    // ---- block reduce ----
    loc_s = waveReduceF(loc_s);
    all_s = waveReduceF(all_s);
    pos_s = waveReduceF(pos_s);
    pc    = waveReduceU(pc);

    __shared__ float sL[4], sA[4], sP[4];
    __shared__ unsigned sC[4];
    if (lane == 0) { sL[wid] = loc_s; sA[wid] = all_s; sP[wid] = pos_s; sC[wid] = pc; }
    __syncthreads();
    if (tid == 0) {
        float L = sL[0] + sL[1] + sL[2] + sL[3];
        float S = sA[0] + sA[1] + sA[2] + sA[3];
        float P = sP[0] + sP[1] + sP[2] + sP[3];
        unsigned C = sC[0] + sC[1] + sC[2] + sC[3];
        partial[b * SUBSX + s] = make_float4(L, S, P, (float)C);
    }
}

// ---------------------------------------------------------------- kernel 2
// Single block. Threads 0..127 each own a batch: reduce the 8 partials,
// apply mining formula (hot path: all-ones neg_mask), block-reduce the mean.
__global__ __launch_bounds__(256) void finalize_kernel(
    const float* __restrict__ cls_out,
    const int*   __restrict__ labels,
    const float4* __restrict__ partial,
    float* __restrict__ out)
{
    const int tid = threadIdx.x;

    __shared__ float sLoc[NBATCH], sPos[NBATCH], sCnt[NBATCH], sConl[NBATCH];
    __shared__ unsigned sK[NBATCH];
    __shared__ unsigned nflag;
    if (tid == 0) nflag = 0;
    __syncthreads();

    if (tid < NBATCH) {
        float loc = 0.f, all = 0.f, pos = 0.f, cnt = 0.f;
        #pragma unroll
        for (int c = 0; c < SUBSX; ++c) {
            float4 p = partial[tid * SUBSX + c];
            loc += p.x; all += p.y; pos += p.z; cnt += p.w;
        }
        unsigned k = 3u * (unsigned)cnt;
        if (k > NANCH) k = NANCH;
        if (k == 0u) k = 3u;
        sLoc[tid] = loc; sPos[tid] = pos; sCnt[tid] = cnt;
        sConl[tid] = all + pos;          // hot path: neg_mask all-ones
        if (k < NANCH) { sK[tid] = k; atomicAdd(&nflag, 1u); }
        else sK[tid] = 0u;
    }
    __syncthreads();

    if (nflag) {
        // cold general path: exact top-k of con_neg per flagged batch
        __shared__ float    rF[256];
        __shared__ unsigned rU[256];
        for (int b2 = 0; b2 < NBATCH; ++b2) {
            unsigned k = sK[b2];
            if (!k) continue;

            auto count_gt = [&](float t) -> unsigned {
                unsigned cc = 0;
                for (int an = tid; an < NANCH; an += 256) {
                    size_t ba = (size_t)b2 * NANCH + an;
                    int lbl = labels[ba];
                    if (lbl > 0) continue;
                    float con = con_from_row(cls_out + ba * NCLS, lbl);
                    if (con > t) cc++;
                }
                rU[tid] = cc; __syncthreads();
                for (int o = 128; o > 0; o >>= 1) {
                    if (tid < o) rU[tid] += rU[tid + o];
                    __syncthreads();
                }
                unsigned r = rU[0]; __syncthreads();
                return r;
            };

            unsigned cpos = count_gt(0.0f);
            float negpart = 0.f;

            if (k <= cpos) {
                unsigned lo = 0u, hi = 0x7F800000u;
                while (hi - lo > 1u) {
                    unsigned mid = lo + (hi - lo) / 2u;
                    unsigned cc = count_gt(__uint_as_float(mid));
                    if (cc >= k) lo = mid; else hi = mid;
                }
                float v = __uint_as_float(hi);   // k-th largest value
                float ss = 0.f; unsigned c1 = 0;
                for (int an = tid; an < NANCH; an += 256) {
                    size_t ba = (size_t)b2 * NANCH + an;
                    int lbl = labels[ba];
                    if (lbl > 0) continue;
                    float con = con_from_row(cls_out + ba * NCLS, lbl);
                    if (con > v) { ss += con; c1++; }
                }
                rF[tid] = ss; rU[tid] = c1; __syncthreads();
                for (int o = 128; o > 0; o >>= 1) {
                    if (tid < o) { rF[tid] += rF[tid + o]; rU[tid] += rU[tid + o]; }
                    __syncthreads();
                }
                negpart = rF[0] + (float)(k - rU[0]) * v;
                __syncthreads();
            } else {
                if (tid == 0) {
                    float np = 0.f;
                    unsigned mrem = k - cpos;
                    for (int an = 0; an < NANCH; ++an) {
                        size_t ba = (size_t)b2 * NANCH + an;
                        int lbl = labels[ba];
                        float con = con_from_row(cls_out + ba * NCLS, lbl);
                        float cneg = (lbl > 0) ? 0.f : con;
                        if (cneg > 0.f) np += con;
                        else if (mrem > 0u) { np += con; mrem--; }
                    }
                    rF[0] = np;
                }
                __syncthreads();
                negpart = rF[0];
                __syncthreads();
            }

            if (tid == 0) sConl[b2] = sPos[b2] + negpart;
            __syncthreads();
        }
    }

    // final mean over batches
    float t = 0.f;
    if (tid < NBATCH) {
        float denom = (sCnt[tid] != 0.f) ? sCnt[tid] : 1.f;
        t = (sLoc[tid] + sConl[tid]) / denom;
    }
    t = waveReduceF(t);
    __shared__ float sW[4];
    const int w = tid >> 6, lane = tid & 63;
    if (lane == 0) sW[w] = t;
    __syncthreads();
    if (tid == 0) out[0] = (sW[0] + sW[1] + sW[2] + sW[3]) * (1.f / NBATCH);
}

// ---------------------------------------------------------------- launch
extern "C" void kernel_launch(void* const* d_in, const int* in_sizes, int n_in,
                              void* d_out, int out_size, void* d_ws, size_t ws_size,
                              hipStream_t stream) {
    const float* loc_out = (const float*)d_in[0];
    const float* cls_out = (const float*)d_in[1];
    const float* loc_lab = (const float*)d_in[2];
    const int*   labels  = (const int*)d_in[3];
    float* out = (float*)d_out;
    float4* partial = (float4*)d_ws;   // 128*8*16 = 16384 B of ws

    dim3 grid(SUBSX, NBATCH);
    anchor_kernel<<<grid, 256, 0, stream>>>(loc_out, cls_out, loc_lab, labels, partial);
    finalize_kernel<<<1, 256, 0, stream>>>(cls_out, labels, partial, out);
}